// Round 7
// baseline (145.080 us; speedup 1.0000x reference)
//
#include <hip/hip_runtime.h>

typedef _Float16 f16;
typedef _Float16 f16x8 __attribute__((ext_vector_type(8)));
typedef _Float16 f16x4 __attribute__((ext_vector_type(4)));
typedef _Float16 f16x2 __attribute__((ext_vector_type(2)));
typedef float f32x4 __attribute__((ext_vector_type(4)));

#define MFMA(a, b, c) __builtin_amdgcn_mfma_f32_16x16x32_f16(a, b, c, 0, 0, 0)
#define PKRTZ(a, b) __builtin_bit_cast(f16x2, __builtin_amdgcn_cvt_pkrtz(a, b))

__device__ __forceinline__ void gload16(const void* g, void* l) {
  __builtin_amdgcn_global_load_lds((const __attribute__((address_space(1))) char*)g,
                                   (__attribute__((address_space(3))) char*)l, 16, 0, 0);
}

// B=2, T=2048, D=1024, H=16, DH=64

// ---------- prep: fp32 -> fp16 convert of hidden ----------
__global__ __launch_bounds__(256) void k_cvt_hidden(const float* __restrict__ x, f16* __restrict__ y) {
  int i = blockIdx.x * 256 + threadIdx.x;
  float4 v = ((const float4*)x)[i];
  f16x4 h; h[0] = (f16)v.x; h[1] = (f16)v.y; h[2] = (f16)v.z; h[3] = (f16)v.w;
  ((f16x4*)y)[i] = h;
}

// ---------- prep: transpose+convert weights [k][n] fp32 -> [n][k] fp16 ----------
__global__ __launch_bounds__(256) void k_cvt_w(const float* __restrict__ w0, const float* __restrict__ w1,
                                               const float* __restrict__ w2, const float* __restrict__ w3,
                                               f16* __restrict__ wt) {
  int z = blockIdx.z;
  const float* w = z == 0 ? w0 : z == 1 ? w1 : z == 2 ? w2 : w3;
  f16* dst = wt + (size_t)z * 1024 * 1024;
  __shared__ float tile[64][65];
  int t = threadIdx.x;
  int k0 = blockIdx.x * 64, n0 = blockIdx.y * 64;
  int cr = t >> 4, cc = (t & 15) * 4;
#pragma unroll
  for (int p = 0; p < 4; p++) {
    int r = cr + p * 16;
    float4 v = *(const float4*)&w[(size_t)(k0 + r) * 1024 + n0 + cc];
    tile[r][cc + 0] = v.x; tile[r][cc + 1] = v.y; tile[r][cc + 2] = v.z; tile[r][cc + 3] = v.w;
  }
  __syncthreads();
#pragma unroll
  for (int p = 0; p < 4; p++) {
    int nn = cr + p * 16;
    f16x4 h;
    h[0] = (f16)tile[cc + 0][nn]; h[1] = (f16)tile[cc + 1][nn];
    h[2] = (f16)tile[cc + 2][nn]; h[3] = (f16)tile[cc + 3][nn];
    *(f16x4*)&dst[(size_t)(n0 + nn) * 1024 + k0 + cc] = h;
  }
}

// ---------- GEMM core: C[128 rows @m0][128 cols] = A[M,K] @ Wrows^T, fp16 in, fp32 acc ----------
template <bool OUTF32>
__device__ __forceinline__ void gemm_core(const f16* __restrict__ A, const f16* __restrict__ Wrows,
                                          const float* __restrict__ bias, int m0,
                                          f16* __restrict__ oh, float* __restrict__ of) {
  __shared__ f16 Al[2][128 * 64];
  __shared__ f16 Bl[2][128 * 64];
  const int t = threadIdx.x;
  const int lane = t & 63, wid = t >> 6;
  const int lr = lane & 15, lg = lane >> 4;
  const int wm = wid >> 1, wn = wid & 1;
  const int lrow = lane >> 3;
  const int cb = (((lane & 7) ^ lrow) << 4);        // pre-swizzled source byte col

  f32x4 acc[4][4] = {};

  auto stage = [&](int k0, int bs) {
#pragma unroll
    for (int it = 0; it < 4; it++) {
      int rbase = it * 32 + wid * 8;                // wave-uniform
      int row = rbase + lrow;
      gload16((const char*)&A[(size_t)(m0 + row) * 1024 + k0] + cb, (char*)&Al[bs][0] + rbase * 128);
      gload16((const char*)&Wrows[(size_t)row * 1024 + k0] + cb, (char*)&Bl[bs][0] + rbase * 128);
    }
  };

  stage(0, 0);
  __syncthreads();
  int cur = 0;
  for (int k0 = 0; k0 < 1024; k0 += 64) {
    if (k0 + 64 < 1024) stage(k0 + 64, cur ^ 1);
    f16x8 af[2][4], bf[2][4];
#pragma unroll
    for (int x = 0; x < 4; x++) {
      int ra = wm * 64 + x * 16 + lr;
      int rb = wn * 64 + x * 16 + lr;
#pragma unroll
      for (int kh = 0; kh < 2; kh++) {
        int ca = (kh * 64 + lg * 16) ^ ((lr & 7) << 4);
        af[kh][x] = *(const f16x8*)((char*)&Al[cur][0] + ra * 128 + ca);
        bf[kh][x] = *(const f16x8*)((char*)&Bl[cur][0] + rb * 128 + ca);
      }
    }
    __builtin_amdgcn_s_setprio(1);
#pragma unroll
    for (int kh = 0; kh < 2; kh++)
#pragma unroll
      for (int mt = 0; mt < 4; mt++)
#pragma unroll
        for (int nt = 0; nt < 4; nt++)
          acc[mt][nt] = MFMA(af[kh][mt], bf[kh][nt], acc[mt][nt]);
    __builtin_amdgcn_s_setprio(0);
    __syncthreads();
    cur ^= 1;
  }
#pragma unroll
  for (int mt = 0; mt < 4; mt++) {
#pragma unroll
    for (int nt = 0; nt < 4; nt++) {
      int col = wn * 64 + nt * 16 + lr;             // local 0..127
      float bcol = bias[col];
#pragma unroll
      for (int e = 0; e < 4; e++) {
        int row = m0 + wm * 64 + mt * 16 + lg * 4 + e;
        float val = acc[mt][nt][e] + bcol;
        if (OUTF32) of[(size_t)row * 1024 + col] = val;
        else        oh[(size_t)row * 1024 + col] = (f16)val;
      }
    }
  }
}

// fused QKV: W' = wt as [3072][1024]; grid (32, 24)
__global__ __launch_bounds__(256, 2) void k_gemm_qkv(const f16* __restrict__ A, const f16* __restrict__ wt,
                                                     const float* __restrict__ bq, const float* __restrict__ bk,
                                                     const float* __restrict__ bv,
                                                     f16* __restrict__ q, f16* __restrict__ k, f16* __restrict__ v) {
  int n0 = blockIdx.y * 128;
  int zsel = n0 >> 10, cbs = n0 & 1023;
  const float* bias = (zsel == 0 ? bq : zsel == 1 ? bk : bv) + cbs;
  f16* dst = (zsel == 0 ? q : zsel == 1 ? k : v) + cbs;
  gemm_core<false>(A, wt + (size_t)n0 * 1024, bias, blockIdx.x * 128, dst, nullptr);
}

__global__ __launch_bounds__(256, 2) void k_gemm_o(const f16* __restrict__ A, const f16* __restrict__ wt3,
                                                   const float* __restrict__ bo, float* __restrict__ out) {
  int n0 = blockIdx.y * 128;
  gemm_core<true>(A, wt3 + (size_t)n0 * 1024, bo + n0, blockIdx.x * 128, nullptr, out + n0);
}

// ---------- RMSNorm + interleaved RoPE (in-place on fp16 q/k), fp32 math ----------
__global__ __launch_bounds__(256) void k_normrope(f16* __restrict__ qh, f16* __restrict__ kh,
                                                  const float* __restrict__ gq, const float* __restrict__ gk,
                                                  const float* __restrict__ cs, const float* __restrict__ sn) {
  int row = blockIdx.x, which = blockIdx.y;
  f16* buf = which ? kh : qh;
  const float* g = which ? gk : gq;
  int t = threadIdx.x, c4 = t * 4;
  f16x4 xv = *(const f16x4*)&buf[(size_t)row * 1024 + c4];
  float x0 = xv[0], x1 = xv[1], x2 = xv[2], x3 = xv[3];
  float ss = x0 * x0 + x1 * x1 + x2 * x2 + x3 * x3;
#pragma unroll
  for (int off = 1; off < 64; off <<= 1) ss += __shfl_xor(ss, off);
  __shared__ float red[4];
  if ((t & 63) == 0) red[t >> 6] = ss;
  __syncthreads();
  float inv = rsqrtf((red[0] + red[1] + red[2] + red[3]) * (1.0f / 1024.0f) + 1e-6f);
  int tt = row & 2047;
  float4 cv = *(const float4*)&cs[(size_t)tt * 1024 + c4];
  float4 sv = *(const float4*)&sn[(size_t)tt * 1024 + c4];
  float4 gv = *(const float4*)&g[c4];
  float y0 = x0 * inv * gv.x, y1 = x1 * inv * gv.y, y2 = x2 * inv * gv.z, y3 = x3 * inv * gv.w;
  f16x4 ov;
  ov[0] = (f16)(y0 * cv.x - y1 * sv.x);
  ov[1] = (f16)(y1 * cv.y + y0 * sv.y);
  ov[2] = (f16)(y2 * cv.z - y3 * sv.z);
  ov[3] = (f16)(y3 * cv.w + y2 * sv.w);
  *(f16x4*)&buf[(size_t)row * 1024 + c4] = ov;
}

// ---------- V transpose: [b,t,h*64+dh] -> [b,h,dh,t] ----------
__global__ __launch_bounds__(256) void k_vtrans(const f16* __restrict__ vh, f16* __restrict__ vt) {
  __shared__ f16 tile[64][65];
  int t = threadIdx.x;
  int t0 = blockIdx.x * 64;
  int bh = blockIdx.y;
  int b = bh >> 4, h = bh & 15;
  int rr = t >> 3, c8 = (t & 7) * 8;
#pragma unroll
  for (int p = 0; p < 2; p++) {
    int r = p * 32 + rr;
    f16x8 v = *(const f16x8*)&vh[(size_t)(b * 2048 + t0 + r) * 1024 + h * 64 + c8];
#pragma unroll
    for (int j = 0; j < 8; j++) tile[r][c8 + j] = v[j];
  }
  __syncthreads();
#pragma unroll
  for (int p = 0; p < 2; p++) {
    int dh = p * 32 + rr;
    f16x8 o;
#pragma unroll
    for (int j = 0; j < 8; j++) o[j] = tile[c8 + j][dh];
    *(f16x8*)&vt[((size_t)bh * 64 + dh) * 2048 + t0 + c8] = o;
  }
}

// ---------- flash attention v6: split-KV x2 for occupancy ----------
// grid 1024: raw&7 = XCD (4 bh per XCD), (raw>>5)&1 = KV half, raw>>6 = q-block.
// Each block: 16 chunks of its KV half; writes normalized partial O (f16) + m,l.
#define ASWZ(row) ((((row) & 3) | (((row) & 8) >> 1)) << 4)

__global__ __launch_bounds__(256, 4) void k_attn(const f16* __restrict__ qh, const f16* __restrict__ kh,
                                                 const f16* __restrict__ vt,
                                                 f16* __restrict__ op0, f16* __restrict__ op1,
                                                 float* __restrict__ ml) {
  __shared__ f16 Kl[2][64 * 64];
  __shared__ f16 Vl[2][64 * 64];
  const int t = threadIdx.x;
  const int lane = t & 63, wid = t >> 6;
  const int lr = lane & 15, lg = lane >> 4;
  const int lgb = lg << 4;
  const int raw = blockIdx.x;
  const int mybh = ((raw & 7) << 2) | ((raw >> 3) & 3);
  const int half = (raw >> 5) & 1;
  const int myq = raw >> 6;                   // [0,16)
  const int b = mybh >> 4, h = mybh & 15;
  const int q0 = myq * 128 + wid * 32;
  const int kvbase = half << 10;              // 0 or 1024
  f16* __restrict__ op = half ? op1 : op0;
  const f16* Qb = qh + ((size_t)(b * 2048 + q0)) * 1024 + h * 64;
  f16x8 qf[2][2];
#pragma unroll
  for (int g = 0; g < 2; g++) {
    qf[g][0] = *(const f16x8*)&Qb[(size_t)(g * 16 + lr) * 1024 + lg * 8];
    qf[g][1] = *(const f16x8*)&Qb[(size_t)(g * 16 + lr) * 1024 + 32 + lg * 8];
  }
  const f16* Kg = kh + ((size_t)b * 2048) * 1024 + h * 64;
  const f16* Vg = vt + ((size_t)mybh) * 64 * 2048;
  const int lrow = lane >> 3;
  const int sg = (lane & 7) << 4;
  const float sc = 0.125f * 1.44269504088896340736f;
  float m[2] = {-1e30f, -1e30f};
  f32x4 acc[2][4] = {};
  f32x4 accl[2] = {};
  const f16 ov1 = (lr == 0) ? (f16)1.0f : (f16)0.0f;
  const f16x8 onesf = {ov1, ov1, ov1, ov1, ov1, ov1, ov1, ov1};

  auto stage = [&](int kvo, int bs) {
#pragma unroll
    for (int i = 0; i < 2; i++) {
      int rbase = (i * 4 + wid) * 8;          // wave-uniform
      int row = rbase + lrow;
      int cswz = sg ^ ASWZ(row);
      gload16((const char*)(Kg + (size_t)(kvo + row) * 1024) + cswz, (char*)&Kl[bs][0] + rbase * 128);
      gload16((const char*)(Vg + (size_t)row * 2048 + kvo) + cswz, (char*)&Vl[bs][0] + rbase * 128);
    }
  };

  stage(kvbase, 0);
  __syncthreads();
  int cur = 0;

  for (int c = 0; c < 16; c++) {
    int kv0 = kvbase + c * 64;
    if (c + 1 < 16) stage(kv0 + 64, cur ^ 1);
    const char* Kb = (const char*)&Kl[cur][0];
    const char* Vb = (const char*)&Vl[cur][0];

    // S^T = K @ Q^T, permuted key rows; K frags shared by both q-groups.
    f32x4 s[2][4];
    __builtin_amdgcn_s_setprio(1);
#pragma unroll
    for (int ks = 0; ks < 4; ks++) {
      int key = ((lr >> 2) << 3) + (lr & 3) + ((ks & 1) << 2) + ((ks >> 1) << 5);
      int sw = ASWZ(key);
      f16x8 kf0 = *(const f16x8*)(Kb + key * 128 + (lgb ^ sw));
      f16x8 kf1 = *(const f16x8*)(Kb + key * 128 + ((64 + lgb) ^ sw));
#pragma unroll
      for (int g = 0; g < 2; g++) {
        f32x4 z = {};
        z = MFMA(kf0, qf[g][0], z);
        z = MFMA(kf1, qf[g][1], z);
        s[g][ks] = z;   // lane: S[qrow=lr(grp g)][key = lg*8+e+(ks&1)*4+(ks>>1)*32]
      }
    }
    __builtin_amdgcn_s_setprio(0);

    union U { f16x8 v; f16x2 h[4]; } u[2][2];
#pragma unroll
    for (int g = 0; g < 2; g++) {
      float smax = fmaxf(fmaxf(s[g][0][0], s[g][0][1]), s[g][0][2]);
      smax = fmaxf(fmaxf(smax, s[g][0][3]), s[g][1][0]);
      smax = fmaxf(fmaxf(smax, s[g][1][1]), s[g][1][2]);
      smax = fmaxf(fmaxf(smax, s[g][1][3]), s[g][2][0]);
      smax = fmaxf(fmaxf(smax, s[g][2][1]), s[g][2][2]);
      smax = fmaxf(fmaxf(smax, s[g][2][3]), s[g][3][0]);
      smax = fmaxf(fmaxf(smax, s[g][3][1]), s[g][3][2]);
      smax = fmaxf(smax, s[g][3][3]);
      smax = fmaxf(smax, __shfl_xor(smax, 16));
      smax = fmaxf(smax, __shfl_xor(smax, 32));
      float smc = smax * sc;

      if (!__all(smc - m[g] <= 8.f)) {        // defer-max
        float mn = fmaxf(m[g], smc);
        float al = exp2f(m[g] - mn);
        m[g] = mn;
        float alq[4];
#pragma unroll
        for (int e = 0; e < 4; e++) alq[e] = __shfl(al, lg * 4 + e);
#pragma unroll
        for (int ds = 0; ds < 4; ds++)
#pragma unroll
          for (int e = 0; e < 4; e++) acc[g][ds][e] *= alq[e];
#pragma unroll
        for (int e = 0; e < 4; e++) accl[g][e] *= alq[e];
      }

#pragma unroll
      for (int ks = 0; ks < 4; ks++) {
        float p0 = exp2f(fmaf(s[g][ks][0], sc, -m[g]));
        float p1 = exp2f(fmaf(s[g][ks][1], sc, -m[g]));
        float p2 = exp2f(fmaf(s[g][ks][2], sc, -m[g]));
        float p3 = exp2f(fmaf(s[g][ks][3], sc, -m[g]));
        u[g][ks >> 1].h[(ks & 1) * 2 + 0] = PKRTZ(p0, p1);
        u[g][ks >> 1].h[(ks & 1) * 2 + 1] = PKRTZ(p2, p3);
      }
    }

    // PV: V frags shared by both groups; denominator via ones-column.
    __builtin_amdgcn_s_setprio(1);
#pragma unroll
    for (int ds = 0; ds < 4; ds++) {
      int vrow = ds * 16 + lr;
      int sw = ASWZ(vrow);
      f16x8 vf0 = *(const f16x8*)(Vb + vrow * 128 + (lgb ^ sw));
      f16x8 vf1 = *(const f16x8*)(Vb + vrow * 128 + ((64 + lgb) ^ sw));
#pragma unroll
      for (int g = 0; g < 2; g++) {
        acc[g][ds] = MFMA(u[g][0].v, vf0, acc[g][ds]);
        acc[g][ds] = MFMA(u[g][1].v, vf1, acc[g][ds]);
      }
    }
#pragma unroll
    for (int g = 0; g < 2; g++) {
      accl[g] = MFMA(u[g][0].v, onesf, accl[g]);
      accl[g] = MFMA(u[g][1].v, onesf, accl[g]);
    }
    __builtin_amdgcn_s_setprio(0);

    __syncthreads();   // drains stage loads + protects LDS reuse
    cur ^= 1;
  }

  // epilogue: normalized partial O + (m, l) per q-row
#pragma unroll
  for (int g = 0; g < 2; g++) {
    int qglob = mybh * 2048 + q0 + g * 16;         // qid base for this group
    if (lg == 0)                                    // lanes 0..15: m of row lr
      ml[(size_t)((half << 16) + qglob + lr) * 2 + 0] = m[g];
    if (lr == 0) {                                  // lanes lg*16: l of rows lg*4+e
#pragma unroll
      for (int e = 0; e < 4; e++)
        ml[(size_t)((half << 16) + qglob + lg * 4 + e) * 2 + 1] = accl[g][e];
    }
#pragma unroll
    for (int e = 0; e < 4; e++) {
      float lf = 1.f / __shfl(accl[g][e], lg << 4);
      size_t row = (size_t)(b * 2048 + q0 + g * 16 + lg * 4 + e);
#pragma unroll
      for (int ds = 0; ds < 4; ds++)
        op[row * 1024 + h * 64 + ds * 16 + lr] = (f16)(acc[g][ds][e] * lf);
    }
  }
}

// ---------- merge the two KV halves ----------
__global__ __launch_bounds__(256) void k_merge(const f16* __restrict__ op0, const f16* __restrict__ op1,
                                               const float* __restrict__ ml, f16* __restrict__ ao) {
  int i = blockIdx.x * 256 + threadIdx.x;   // 524288 threads, 8 f16 each
  int qid = i >> 3, seg = i & 7;
  float m0 = ml[(size_t)qid * 2], l0 = ml[(size_t)qid * 2 + 1];
  float m1 = ml[(size_t)(65536 + qid) * 2], l1 = ml[(size_t)(65536 + qid) * 2 + 1];
  float mm = fmaxf(m0, m1);
  float w0 = l0 * exp2f(m0 - mm), w1 = l1 * exp2f(m1 - mm);
  float inv = 1.f / (w0 + w1);
  w0 *= inv; w1 *= inv;
  int bh = qid >> 11, tt = qid & 2047;
  size_t addr = (((size_t)(bh >> 4) * 2048 + tt) * 1024 + (bh & 15) * 64 + seg * 8) / 8;
  f16x8 a = ((const f16x8*)op0)[addr];
  f16x8 bb = ((const f16x8*)op1)[addr];
  f16x8 o;
#pragma unroll
  for (int j = 0; j < 8; j++) o[j] = (f16)(w0 * (float)a[j] + w1 * (float)bb[j]);
  ((f16x8*)ao)[addr] = o;
}

extern "C" void kernel_launch(void* const* d_in, const int* in_sizes, int n_in,
                              void* d_out, int out_size, void* d_ws, size_t ws_size,
                              hipStream_t stream) {
  const float* hid  = (const float*)d_in[0];
  const float* cosb = (const float*)d_in[1];
  const float* sinb = (const float*)d_in[2];
  const float* wq = (const float*)d_in[3];
  const float* bq = (const float*)d_in[4];
  const float* wk = (const float*)d_in[5];
  const float* bk = (const float*)d_in[6];
  const float* wv = (const float*)d_in[7];
  const float* bv = (const float*)d_in[8];
  const float* gq = (const float*)d_in[9];
  const float* gk = (const float*)d_in[10];
  const float* wo = (const float*)d_in[11];
  const float* bo = (const float*)d_in[12];
  float* out = (float*)d_out;

  char* ws = (char*)d_ws;
  f16* aH  = (f16*)(ws);                          // 8 MB: hidden fp16; reused as op1 after QKV
  f16* wt  = (f16*)(ws + ((size_t)8 << 20));      // 8 MB: 4 weights transposed [n][k] fp16
  f16* qh  = (f16*)(ws + ((size_t)16 << 20));     // 8 MB
  f16* khb = (f16*)(ws + ((size_t)24 << 20));     // 8 MB
  f16* vhb = (f16*)(ws + ((size_t)32 << 20));     // 8 MB: V; reused as op0 after vtrans
  f16* vtb = (f16*)(ws + ((size_t)40 << 20));     // 8 MB: V^T [b,h,dh,t]
  f16* ao  = (f16*)(ws + ((size_t)48 << 20));     // 8 MB: merged attention out
  float* ml = (float*)(ws + ((size_t)56 << 20));  // 1 MB: [2][65536][m,l] f32

  k_cvt_hidden<<<dim3(4096), dim3(256), 0, stream>>>(hid, aH);
  k_cvt_w<<<dim3(16, 16, 4), dim3(256), 0, stream>>>(wq, wk, wv, wo, wt);
  k_gemm_qkv<<<dim3(32, 24), dim3(256), 0, stream>>>(aH, wt, bq, bk, bv, qh, khb, vhb);
  k_normrope<<<dim3(4096, 2), dim3(256), 0, stream>>>(qh, khb, gq, gk, cosb, sinb);
  k_vtrans<<<dim3(32, 32), dim3(256), 0, stream>>>(vhb, vtb);
  k_attn<<<dim3(1024), dim3(256), 0, stream>>>(qh, khb, vtb, /*op0=*/vhb, /*op1=*/aH, ml);
  k_merge<<<dim3(2048), dim3(256), 0, stream>>>(vhb, aH, ml, ao);
  k_gemm_o<<<dim3(32, 8), dim3(256), 0, stream>>>(ao, wt + (size_t)3 * 1024 * 1024, bo, out);
}